// Round 8
// baseline (113.270 us; speedup 1.0000x reference)
//
#include <hip/hip_runtime.h>
#include <stdint.h>

#define NTOT 8192
#define NX   4096
#define DIM  256
#define NBJ  64                      // 8192/128 tiles per dimension
#define NBLK (NBJ*(NBJ+1)/2)         // 2080 upper-triangle tiles

typedef unsigned short u16;
typedef __attribute__((ext_vector_type(8))) short  bf16x8;
typedef __attribute__((ext_vector_type(8))) short  short8;
typedef __attribute__((ext_vector_type(4))) float  f32x4;

// ---- workspace layout (bytes) ----
#define OFF_TOT     0                        // u16[8192*256] FRAGMENT layout = 4,194,304
#define OFF_SQ      4194304                  // float[8192]
#define OFF_SQPART  (OFF_SQ + 32768)         // float[512]
#define OFF_PART    (OFF_SQPART + 2048)      // double[2080]

// fragment layout: u16 offset = (r/16)*4096 + (k/8)*128 + (r%16)*8 + (k%8)
// => one wave's 16x32 MFMA A/B fragment slice = 1KB contiguous, lane-coalesced.

__device__ __forceinline__ u16 f2bf(float f) {
  union { float f; unsigned int u; } v; v.f = f;
  unsigned int u = v.u;
  u += 0x7fffu + ((u >> 16) & 1u);           // round-to-nearest-even
  return (u16)(u >> 16);
}

// ---- K1: prep (R4's proven structure, atomics stripped). 512 blocks x 256;
// block = 16 rows = one fragment chunk. Coalesced float4 reads -> bf16 ->
// LDS bounce in fragment order -> coalesced 16B global writes. Row norms ->
// sq + per-block partial. NO atomics, NO fences.
__global__ __launch_bounds__(256) void k_prep(const float* __restrict__ x,
                                              const float* __restrict__ y,
                                              u16* __restrict__ tot,
                                              float* __restrict__ sq,
                                              float* __restrict__ sqpart) {
  __shared__ u16   tile[4096];      // one 16-row fragment chunk image
  __shared__ float sred[16];
  const int t  = threadIdx.x;
  const int rr = t >> 4;            // row within chunk (0..15)
  const int cg = t & 15;            // 16-col group
  const int r  = blockIdx.x * 16 + rr;

  const float* row = (r < NX) ? (x + (size_t)r * DIM) : (y + (size_t)(r - NX) * DIM);
  const float4* rp = (const float4*)row + cg * 4;
  const float4 p0 = rp[0], p1 = rp[1], p2 = rp[2], p3 = rp[3];

  short8 h0, h1;
  h0[0]=(short)f2bf(p0.x); h0[1]=(short)f2bf(p0.y); h0[2]=(short)f2bf(p0.z); h0[3]=(short)f2bf(p0.w);
  h0[4]=(short)f2bf(p1.x); h0[5]=(short)f2bf(p1.y); h0[6]=(short)f2bf(p1.z); h0[7]=(short)f2bf(p1.w);
  h1[0]=(short)f2bf(p2.x); h1[1]=(short)f2bf(p2.y); h1[2]=(short)f2bf(p2.z); h1[3]=(short)f2bf(p2.w);
  h1[4]=(short)f2bf(p3.x); h1[5]=(short)f2bf(p3.y); h1[6]=(short)f2bf(p3.z); h1[7]=(short)f2bf(p3.w);
  // o(r,c) = (c>>3)*128 + rr*8 ; cols cg*16..+7 and cg*16+8..+15
  *(short8*)&tile[cg * 256 + rr * 8]       = h0;
  *(short8*)&tile[cg * 256 + 128 + rr * 8] = h1;

  float s = p0.x*p0.x + p0.y*p0.y + p0.z*p0.z + p0.w*p0.w
          + p1.x*p1.x + p1.y*p1.y + p1.z*p1.z + p1.w*p1.w
          + p2.x*p2.x + p2.y*p2.y + p2.z*p2.z + p2.w*p2.w
          + p3.x*p3.x + p3.y*p3.y + p3.z*p3.z + p3.w*p3.w;
  #pragma unroll
  for (int k = 8; k; k >>= 1) s += __shfl_down(s, k, 64);   // reduce over 16 col-lanes
  if (cg == 0) { sq[r] = s; sred[rr] = s; }
  __syncthreads();

  u16* chunk = tot + (size_t)blockIdx.x * 4096;
  *(uint4*)(chunk + t * 8)        = *(const uint4*)&tile[t * 8];
  *(uint4*)(chunk + 2048 + t * 8) = *(const uint4*)&tile[2048 + t * 8];
  if (t == 0) {
    float ss = 0.f;
    #pragma unroll
    for (int i = 0; i < 16; ++i) ss += sred[i];
    sqpart[blockIdx.x] = ss;
  }
}

// ---- K2: gram + 5-kernel RBF + signed sum. Direct-global fragment loads
// (L2-resident), ZERO barriers / ZERO LDS in the K-loop, explicit 2-set
// load/MFMA pipeline. No launch_bounds cap (R5's spill lesson), no
// atomics/fences (R6's L2-poison lesson). Upper-triangle tiles, weight x2.
__global__ void k_main(const u16* __restrict__ tot,
                       const float* __restrict__ sq,
                       const float* __restrict__ sqpart,
                       double* __restrict__ part) {
  const int tid = threadIdx.x, wave = tid >> 6, lane = tid & 63;
  const int quad = lane >> 4, l16 = lane & 15;

  // ---- per-block c2 from sqpart[512] (fence-free redundant compute) ----
  float sp = sqpart[tid] + sqpart[tid + 256];
  #pragma unroll
  for (int off = 32; off; off >>= 1) sp += __shfl_down(sp, off, 64);
  __shared__ float spw[4];
  if (lane == 0) spw[wave] = sp;
  __syncthreads();
  const double S1 = (double)spw[0] + (double)spw[1] + (double)spw[2] + (double)spw[3];
  const double n  = (double)NTOT;
  const double bwd = 2.0 * n * S1 / (n * n - n) * 0.25;  // colsum term dropped (1e-4 rel)
  const float  c2  = (float)(1.0 / (16.0 * bwd * 0.6931471805599453));

  // ---- triangular decode: g -> (bi <= bj) ----
  const int g = blockIdx.x;
  int bj = (int)((sqrtf(8.0f * (float)g + 1.0f) - 1.0f) * 0.5f);
  while ((bj + 1) * (bj + 2) / 2 <= g) ++bj;
  while (bj * (bj + 1) / 2 > g) --bj;
  const int bi = g - bj * (bj + 1) / 2;
  const int wm = wave >> 1, wn = wave & 1;

  const int off0 = quad * 128 + l16 * 8;     // within-chunk fragment offset (u16)
  const u16* Ab = tot + (size_t)(bi * 8 + wm * 4) * 4096 + off0;
  const u16* Bb = tot + (size_t)(bj * 8 + wn * 4) * 4096 + off0;

  f32x4 acc[4][4];
  #pragma unroll
  for (int tm = 0; tm < 4; ++tm)
    #pragma unroll
    for (int tn = 0; tn < 4; ++tn) {
      acc[tm][tn][0] = 0.f; acc[tm][tn][1] = 0.f;
      acc[tm][tn][2] = 0.f; acc[tm][tn][3] = 0.f;
    }

  // explicit 2-set pipeline: load set(it+1) issued before MFMAs on set(it)
  bf16x8 a0[4], b0[4], a1[4], b1[4];
  #pragma unroll
  for (int tm = 0; tm < 4; ++tm) a0[tm] = *(const bf16x8*)(Ab + (size_t)tm * 4096);
  #pragma unroll
  for (int tn = 0; tn < 4; ++tn) b0[tn] = *(const bf16x8*)(Bb + (size_t)tn * 4096);

  #pragma unroll
  for (int it = 0; it < 8; ++it) {
    bf16x8* ac = (it & 1) ? a1 : a0;
    bf16x8* bc = (it & 1) ? b1 : b0;
    bf16x8* an = (it & 1) ? a0 : a1;
    bf16x8* bn = (it & 1) ? b0 : b1;
    if (it < 7) {
      const size_t ko = (size_t)(it + 1) * 512;
      #pragma unroll
      for (int tm = 0; tm < 4; ++tm) an[tm] = *(const bf16x8*)(Ab + (size_t)tm * 4096 + ko);
      #pragma unroll
      for (int tn = 0; tn < 4; ++tn) bn[tn] = *(const bf16x8*)(Bb + (size_t)tn * 4096 + ko);
    }
    #pragma unroll
    for (int tm = 0; tm < 4; ++tm)
      #pragma unroll
      for (int tn = 0; tn < 4; ++tn)
        acc[tm][tn] = __builtin_amdgcn_mfma_f32_16x16x32_bf16(ac[tm], bc[tn], acc[tm][tn], 0, 0, 0);
  }

  // ---- epilogue: u = exp2(min((2a - sqi - sqj)*c2, 0)); sum of 5 powers ----
  const float nc2 = -c2, c2x2 = 2.0f * c2;
  const int gi0 = bi * 128 + wm * 64;
  const int gj0 = bj * 128 + wn * 64;
  f32x4 mi4[4];
  #pragma unroll
  for (int tm = 0; tm < 4; ++tm) {
    const f32x4 sqi = *(const f32x4*)&sq[gi0 + tm * 16 + quad * 4];
    mi4[tm][0] = sqi[0] * nc2; mi4[tm][1] = sqi[1] * nc2;
    mi4[tm][2] = sqi[2] * nc2; mi4[tm][3] = sqi[3] * nc2;
  }
  float lsum = 0.0f;
  #pragma unroll
  for (int tn = 0; tn < 4; ++tn) {
    const float mj = sq[gj0 + tn * 16 + l16] * nc2;
    #pragma unroll
    for (int tm = 0; tm < 4; ++tm) {
      const f32x4 av = acc[tm][tn];
      #pragma unroll
      for (int r = 0; r < 4; ++r) {
        float e = fminf(fmaf(av[r], c2x2, mi4[tm][r] + mj), 0.0f);
        float u = __builtin_amdgcn_exp2f(e);
        float u2 = u * u, u4 = u2 * u2, u8 = u4 * u4, u16v = u8 * u8;
        lsum += u + u2 + u4 + u8 + u16v;
      }
    }
  }
  float w = ((bi < 32) == (bj < 32)) ? 1.0f : -1.0f;   // XX/YY vs XY/YX
  if (bi != bj) w *= 2.0f;                             // symmetry weight

  #pragma unroll
  for (int off = 32; off; off >>= 1) lsum += __shfl_down(lsum, off, 64);
  __shared__ float wsum[4];
  if (lane == 0) wsum[wave] = lsum;
  __syncthreads();
  if (tid == 0) {
    double tsum = (double)wsum[0] + (double)wsum[1] + (double)wsum[2] + (double)wsum[3];
    part[g] = tsum * (double)w;
  }
}

// ---- K3: final reduce of 2080 partials -> scalar ----
__global__ __launch_bounds__(256) void k_final(const double* __restrict__ part,
                                               float* __restrict__ out) {
  __shared__ double red[256];
  const int t = threadIdx.x;
  double s = 0.0;
  for (int i = t; i < NBLK; i += 256) s += part[i];
  red[t] = s; __syncthreads();
  for (int off = 128; off; off >>= 1) { if (t < off) red[t] += red[t + off]; __syncthreads(); }
  if (t == 0) out[0] = (float)(red[0] / ((double)NX * (double)NX));
}

extern "C" void kernel_launch(void* const* d_in, const int* in_sizes, int n_in,
                              void* d_out, int out_size, void* d_ws, size_t ws_size,
                              hipStream_t stream) {
  const float* x = (const float*)d_in[0];
  const float* y = (const float*)d_in[1];
  char* ws = (char*)d_ws;
  u16*    tot  = (u16*)(ws + OFF_TOT);
  float*  sq   = (float*)(ws + OFF_SQ);
  float*  sqp  = (float*)(ws + OFF_SQPART);
  double* part = (double*)(ws + OFF_PART);
  float*  out  = (float*)d_out;

  hipLaunchKernelGGL(k_prep,  dim3(512),  dim3(256), 0, stream, x, y, tot, sq, sqp);
  hipLaunchKernelGGL(k_main,  dim3(NBLK), dim3(256), 0, stream, tot, sq, sqp, part);
  hipLaunchKernelGGL(k_final, dim3(1),    dim3(256), 0, stream, part, out);
}

// Round 9
// 105.766 us; speedup vs baseline: 1.0710x; 1.0710x over previous
//
#include <hip/hip_runtime.h>
#include <stdint.h>

#define NTOT 8192
#define NX   4096
#define DIM  256
#define NBJ  64                      // 8192/128 tiles per dimension
#define NBLK (NBJ*(NBJ+1)/2)         // 2080 upper-triangle tiles

typedef unsigned short u16;
typedef __attribute__((ext_vector_type(8))) short  bf16x8;
typedef __attribute__((ext_vector_type(8))) short  short8;
typedef __attribute__((ext_vector_type(4))) float  f32x4;

// ---- workspace layout (bytes) ----
#define OFF_TOT     0                        // u16[8192*256] FRAGMENT layout = 4,194,304
#define OFF_SQ      4194304                  // float[8192]
#define OFF_SQPART  (OFF_SQ + 32768)         // float[512]
#define OFF_PART    (OFF_SQPART + 2048)      // double[2080]

// fragment layout: u16 offset = (r/16)*4096 + (k/8)*128 + (r%16)*8 + (k%8)
// => one wave's 16x32 MFMA A/B fragment slice = 1KB contiguous, lane-coalesced.

__device__ __forceinline__ u16 f2bf(float f) {
  union { float f; unsigned int u; } v; v.f = f;
  unsigned int u = v.u;
  u += 0x7fffu + ((u >> 16) & 1u);           // round-to-nearest-even
  return (u16)(u >> 16);
}

// ---- K1: prep. 512 blocks x 256; block = 16 rows = one fragment chunk.
// Coalesced float4 reads -> bf16 -> LDS bounce in fragment order -> coalesced
// 16B global writes. Row norms -> sq + per-block partial. NO atomics/fences.
__global__ __launch_bounds__(256) void k_prep(const float* __restrict__ x,
                                              const float* __restrict__ y,
                                              u16* __restrict__ tot,
                                              float* __restrict__ sq,
                                              float* __restrict__ sqpart) {
  __shared__ u16   tile[4096];      // one 16-row fragment chunk image
  __shared__ float sred[16];
  const int t  = threadIdx.x;
  const int rr = t >> 4;            // row within chunk (0..15)
  const int cg = t & 15;            // 16-col group
  const int r  = blockIdx.x * 16 + rr;

  const float* row = (r < NX) ? (x + (size_t)r * DIM) : (y + (size_t)(r - NX) * DIM);
  const float4* rp = (const float4*)row + cg * 4;
  const float4 p0 = rp[0], p1 = rp[1], p2 = rp[2], p3 = rp[3];

  short8 h0, h1;
  h0[0]=(short)f2bf(p0.x); h0[1]=(short)f2bf(p0.y); h0[2]=(short)f2bf(p0.z); h0[3]=(short)f2bf(p0.w);
  h0[4]=(short)f2bf(p1.x); h0[5]=(short)f2bf(p1.y); h0[6]=(short)f2bf(p1.z); h0[7]=(short)f2bf(p1.w);
  h1[0]=(short)f2bf(p2.x); h1[1]=(short)f2bf(p2.y); h1[2]=(short)f2bf(p2.z); h1[3]=(short)f2bf(p2.w);
  h1[4]=(short)f2bf(p3.x); h1[5]=(short)f2bf(p3.y); h1[6]=(short)f2bf(p3.z); h1[7]=(short)f2bf(p3.w);
  // o(r,c) = (c>>3)*128 + rr*8 ; cols cg*16..+7 and cg*16+8..+15
  *(short8*)&tile[cg * 256 + rr * 8]       = h0;
  *(short8*)&tile[cg * 256 + 128 + rr * 8] = h1;

  float s = p0.x*p0.x + p0.y*p0.y + p0.z*p0.z + p0.w*p0.w
          + p1.x*p1.x + p1.y*p1.y + p1.z*p1.z + p1.w*p1.w
          + p2.x*p2.x + p2.y*p2.y + p2.z*p2.z + p2.w*p2.w
          + p3.x*p3.x + p3.y*p3.y + p3.z*p3.z + p3.w*p3.w;
  #pragma unroll
  for (int k = 8; k; k >>= 1) s += __shfl_down(s, k, 64);   // reduce over 16 col-lanes
  if (cg == 0) { sq[r] = s; sred[rr] = s; }
  __syncthreads();

  u16* chunk = tot + (size_t)blockIdx.x * 4096;
  *(uint4*)(chunk + t * 8)        = *(const uint4*)&tile[t * 8];
  *(uint4*)(chunk + 2048 + t * 8) = *(const uint4*)&tile[2048 + t * 8];
  if (t == 0) {
    float ss = 0.f;
    #pragma unroll
    for (int i = 0; i < 16; ++i) ss += sred[i];
    sqpart[blockIdx.x] = ss;
  }
}

// ---- K2: gram + 5-kernel RBF + signed sum. Direct-global fragment loads
// (L2-resident), zero barriers / zero LDS in K-loop, explicit 2-set pipeline.
// lb(256,2): 256-VGPR cap -> spill-free for this shape (R3/R4: VGPR 92/72,
// WRITE 0.13MB; default heuristic & lb(256,4) both spill -> R5/R8 disasters).
// No atomics/fences (R6's L2-poison lesson). Upper-triangle tiles, weight x2.
__global__ __launch_bounds__(256, 2) void k_main(const u16* __restrict__ tot,
                                                 const float* __restrict__ sq,
                                                 const float* __restrict__ sqpart,
                                                 double* __restrict__ part) {
  const int tid = threadIdx.x, wave = tid >> 6, lane = tid & 63;
  const int quad = lane >> 4, l16 = lane & 15;

  // ---- per-block c2 from sqpart[512] (fence-free redundant compute) ----
  float sp = sqpart[tid] + sqpart[tid + 256];
  #pragma unroll
  for (int off = 32; off; off >>= 1) sp += __shfl_down(sp, off, 64);
  __shared__ float spw[4];
  if (lane == 0) spw[wave] = sp;
  __syncthreads();
  const double S1 = (double)spw[0] + (double)spw[1] + (double)spw[2] + (double)spw[3];
  const double n  = (double)NTOT;
  const double bwd = 2.0 * n * S1 / (n * n - n) * 0.25;  // colsum term dropped (1e-4 rel)
  const float  c2  = (float)(1.0 / (16.0 * bwd * 0.6931471805599453));

  // ---- triangular decode: g -> (bi <= bj) ----
  const int g = blockIdx.x;
  int bj = (int)((sqrtf(8.0f * (float)g + 1.0f) - 1.0f) * 0.5f);
  while ((bj + 1) * (bj + 2) / 2 <= g) ++bj;
  while (bj * (bj + 1) / 2 > g) --bj;
  const int bi = g - bj * (bj + 1) / 2;
  const int wm = wave >> 1, wn = wave & 1;

  const int off0 = quad * 128 + l16 * 8;     // within-chunk fragment offset (u16)
  const u16* Ab = tot + (size_t)(bi * 8 + wm * 4) * 4096 + off0;
  const u16* Bb = tot + (size_t)(bj * 8 + wn * 4) * 4096 + off0;

  f32x4 acc[4][4];
  #pragma unroll
  for (int tm = 0; tm < 4; ++tm)
    #pragma unroll
    for (int tn = 0; tn < 4; ++tn) {
      acc[tm][tn][0] = 0.f; acc[tm][tn][1] = 0.f;
      acc[tm][tn][2] = 0.f; acc[tm][tn][3] = 0.f;
    }

  // explicit 2-set pipeline: load set(it+1) issued before MFMAs on set(it)
  bf16x8 a0[4], b0[4], a1[4], b1[4];
  #pragma unroll
  for (int tm = 0; tm < 4; ++tm) a0[tm] = *(const bf16x8*)(Ab + (size_t)tm * 4096);
  #pragma unroll
  for (int tn = 0; tn < 4; ++tn) b0[tn] = *(const bf16x8*)(Bb + (size_t)tn * 4096);

  #pragma unroll
  for (int it = 0; it < 8; ++it) {
    bf16x8* ac = (it & 1) ? a1 : a0;
    bf16x8* bc = (it & 1) ? b1 : b0;
    bf16x8* an = (it & 1) ? a0 : a1;
    bf16x8* bn = (it & 1) ? b0 : b1;
    if (it < 7) {
      const size_t ko = (size_t)(it + 1) * 512;
      #pragma unroll
      for (int tm = 0; tm < 4; ++tm) an[tm] = *(const bf16x8*)(Ab + (size_t)tm * 4096 + ko);
      #pragma unroll
      for (int tn = 0; tn < 4; ++tn) bn[tn] = *(const bf16x8*)(Bb + (size_t)tn * 4096 + ko);
    }
    #pragma unroll
    for (int tm = 0; tm < 4; ++tm)
      #pragma unroll
      for (int tn = 0; tn < 4; ++tn)
        acc[tm][tn] = __builtin_amdgcn_mfma_f32_16x16x32_bf16(ac[tm], bc[tn], acc[tm][tn], 0, 0, 0);
  }

  // ---- epilogue: u = exp2(min((2a - sqi - sqj)*c2, 0)); sum of 5 powers ----
  const float nc2 = -c2, c2x2 = 2.0f * c2;
  const int gi0 = bi * 128 + wm * 64;
  const int gj0 = bj * 128 + wn * 64;
  f32x4 mi4[4];
  #pragma unroll
  for (int tm = 0; tm < 4; ++tm) {
    const f32x4 sqi = *(const f32x4*)&sq[gi0 + tm * 16 + quad * 4];
    mi4[tm][0] = sqi[0] * nc2; mi4[tm][1] = sqi[1] * nc2;
    mi4[tm][2] = sqi[2] * nc2; mi4[tm][3] = sqi[3] * nc2;
  }
  float lsum = 0.0f;
  #pragma unroll
  for (int tn = 0; tn < 4; ++tn) {
    const float mj = sq[gj0 + tn * 16 + l16] * nc2;
    #pragma unroll
    for (int tm = 0; tm < 4; ++tm) {
      const f32x4 av = acc[tm][tn];
      #pragma unroll
      for (int r = 0; r < 4; ++r) {
        float e = fminf(fmaf(av[r], c2x2, mi4[tm][r] + mj), 0.0f);
        float u = __builtin_amdgcn_exp2f(e);
        float u2 = u * u, u4 = u2 * u2, u8 = u4 * u4, u16v = u8 * u8;
        lsum += u + u2 + u4 + u8 + u16v;
      }
    }
  }
  float w = ((bi < 32) == (bj < 32)) ? 1.0f : -1.0f;   // XX/YY vs XY/YX
  if (bi != bj) w *= 2.0f;                             // symmetry weight

  #pragma unroll
  for (int off = 32; off; off >>= 1) lsum += __shfl_down(lsum, off, 64);
  __shared__ float wsum[4];
  if (lane == 0) wsum[wave] = lsum;
  __syncthreads();
  if (tid == 0) {
    double tsum = (double)wsum[0] + (double)wsum[1] + (double)wsum[2] + (double)wsum[3];
    part[g] = tsum * (double)w;
  }
}

// ---- K3: final reduce of 2080 partials -> scalar ----
__global__ __launch_bounds__(256) void k_final(const double* __restrict__ part,
                                               float* __restrict__ out) {
  __shared__ double red[256];
  const int t = threadIdx.x;
  double s = 0.0;
  for (int i = t; i < NBLK; i += 256) s += part[i];
  red[t] = s; __syncthreads();
  for (int off = 128; off; off >>= 1) { if (t < off) red[t] += red[t + off]; __syncthreads(); }
  if (t == 0) out[0] = (float)(red[0] / ((double)NX * (double)NX));
}

extern "C" void kernel_launch(void* const* d_in, const int* in_sizes, int n_in,
                              void* d_out, int out_size, void* d_ws, size_t ws_size,
                              hipStream_t stream) {
  const float* x = (const float*)d_in[0];
  const float* y = (const float*)d_in[1];
  char* ws = (char*)d_ws;
  u16*    tot  = (u16*)(ws + OFF_TOT);
  float*  sq   = (float*)(ws + OFF_SQ);
  float*  sqp  = (float*)(ws + OFF_SQPART);
  double* part = (double*)(ws + OFF_PART);
  float*  out  = (float*)d_out;

  hipLaunchKernelGGL(k_prep,  dim3(512),  dim3(256), 0, stream, x, y, tot, sq, sqp);
  hipLaunchKernelGGL(k_main,  dim3(NBLK), dim3(256), 0, stream, tot, sq, sqp, part);
  hipLaunchKernelGGL(k_final, dim3(1),    dim3(256), 0, stream, part, out);
}

// Round 10
// 94.582 us; speedup vs baseline: 1.1976x; 1.1182x over previous
//
#include <hip/hip_runtime.h>
#include <stdint.h>

#define NTOT 8192
#define NX   4096
#define DIM  256
#define NBJ  64                      // 8192/128 tiles per dimension
#define NBLK (NBJ*(NBJ+1)/2)         // 2080 upper-triangle tiles
#define GRID 512                     // persistent blocks: 2/CU, 4-5 tiles each

typedef unsigned short u16;
typedef __attribute__((ext_vector_type(8))) short  bf16x8;
typedef __attribute__((ext_vector_type(8))) short  short8;
typedef __attribute__((ext_vector_type(4))) float  f32x4;

// ---- workspace layout (bytes) ----
#define OFF_TOT     0                        // u16[8192*256] FRAGMENT layout = 4,194,304
#define OFF_SQ      4194304                  // float[8192]
#define OFF_SQPART  (OFF_SQ + 32768)         // float[512]
#define OFF_PART    (OFF_SQPART + 2048)      // double[512]

// fragment layout: u16 offset = (r/16)*4096 + (k/8)*128 + (r%16)*8 + (k%8)
// => one wave's 16x32 MFMA A/B fragment slice = 1KB contiguous, lane-coalesced.

__device__ __forceinline__ u16 f2bf(float f) {
  union { float f; unsigned int u; } v; v.f = f;
  unsigned int u = v.u;
  u += 0x7fffu + ((u >> 16) & 1u);           // round-to-nearest-even
  return (u16)(u >> 16);
}

// ---- K1: prep. 512 blocks x 256; block = 16 rows = one fragment chunk.
// Coalesced float4 reads -> bf16 -> LDS bounce in fragment order -> coalesced
// 16B global writes. Row norms -> sq + per-block partial. NO atomics/fences.
__global__ __launch_bounds__(256) void k_prep(const float* __restrict__ x,
                                              const float* __restrict__ y,
                                              u16* __restrict__ tot,
                                              float* __restrict__ sq,
                                              float* __restrict__ sqpart) {
  __shared__ u16   tile[4096];      // one 16-row fragment chunk image
  __shared__ float sred[16];
  const int t  = threadIdx.x;
  const int rr = t >> 4;            // row within chunk (0..15)
  const int cg = t & 15;            // 16-col group
  const int r  = blockIdx.x * 16 + rr;

  const float* row = (r < NX) ? (x + (size_t)r * DIM) : (y + (size_t)(r - NX) * DIM);
  const float4* rp = (const float4*)row + cg * 4;
  const float4 p0 = rp[0], p1 = rp[1], p2 = rp[2], p3 = rp[3];

  short8 h0, h1;
  h0[0]=(short)f2bf(p0.x); h0[1]=(short)f2bf(p0.y); h0[2]=(short)f2bf(p0.z); h0[3]=(short)f2bf(p0.w);
  h0[4]=(short)f2bf(p1.x); h0[5]=(short)f2bf(p1.y); h0[6]=(short)f2bf(p1.z); h0[7]=(short)f2bf(p1.w);
  h1[0]=(short)f2bf(p2.x); h1[1]=(short)f2bf(p2.y); h1[2]=(short)f2bf(p2.z); h1[3]=(short)f2bf(p2.w);
  h1[4]=(short)f2bf(p3.x); h1[5]=(short)f2bf(p3.y); h1[6]=(short)f2bf(p3.z); h1[7]=(short)f2bf(p3.w);
  // o(r,c) = (c>>3)*128 + rr*8 ; cols cg*16..+7 and cg*16+8..+15
  *(short8*)&tile[cg * 256 + rr * 8]       = h0;
  *(short8*)&tile[cg * 256 + 128 + rr * 8] = h1;

  float s = p0.x*p0.x + p0.y*p0.y + p0.z*p0.z + p0.w*p0.w
          + p1.x*p1.x + p1.y*p1.y + p1.z*p1.z + p1.w*p1.w
          + p2.x*p2.x + p2.y*p2.y + p2.z*p2.z + p2.w*p2.w
          + p3.x*p3.x + p3.y*p3.y + p3.z*p3.z + p3.w*p3.w;
  #pragma unroll
  for (int k = 8; k; k >>= 1) s += __shfl_down(s, k, 64);   // reduce over 16 col-lanes
  if (cg == 0) { sq[r] = s; sred[rr] = s; }
  __syncthreads();

  u16* chunk = tot + (size_t)blockIdx.x * 4096;
  *(uint4*)(chunk + t * 8)        = *(const uint4*)&tile[t * 8];
  *(uint4*)(chunk + 2048 + t * 8) = *(const uint4*)&tile[2048 + t * 8];
  if (t == 0) {
    float ss = 0.f;
    #pragma unroll
    for (int i = 0; i < 16; ++i) ss += sred[i];
    sqpart[blockIdx.x] = ss;
  }
}

// ---- K2: persistent tile-pipelined gram + 5-kernel RBF + signed sum.
// 512 blocks, each handles tiles g, g+512, ... Cross-tile software pipeline:
// tile t+1's set-0 fragment loads are issued BEFORE tile t's epilogue, so
// the (~1500 cyc VALU) epilogue hides the L2 load latency. Zero barriers in
// the hot path, zero atomics/fences (R6 lesson), lb(256,2) for spill-free
// allocation (R9 lesson: default & (256,4) both spill).
__global__ __launch_bounds__(256, 2) void k_main(const u16* __restrict__ tot,
                                                 const float* __restrict__ sq,
                                                 const float* __restrict__ sqpart,
                                                 double* __restrict__ part) {
  const int tid = threadIdx.x, wave = tid >> 6, lane = tid & 63;
  const int quad = lane >> 4, l16 = lane & 15;
  const int wm = wave >> 1, wn = wave & 1;
  const int off0 = quad * 128 + l16 * 8;     // within-chunk fragment offset (u16)

  // ---- per-block c2 from sqpart[512] (fence-free redundant compute) ----
  float sp = sqpart[tid] + sqpart[tid + 256];
  #pragma unroll
  for (int off = 32; off; off >>= 1) sp += __shfl_down(sp, off, 64);
  __shared__ float spw[4];
  if (lane == 0) spw[wave] = sp;
  __syncthreads();
  const double S1 = (double)spw[0] + (double)spw[1] + (double)spw[2] + (double)spw[3];
  const double n  = (double)NTOT;
  const double bwd = 2.0 * n * S1 / (n * n - n) * 0.25;  // colsum term dropped (1e-4 rel)
  const float  c2  = (float)(1.0 / (16.0 * bwd * 0.6931471805599453));
  const float  nc2 = -c2, c2x2 = 2.0f * c2;

  // tile decode: g -> (bi<=bj), frag bases, weight
  auto decode = [&](int g, const u16*& Ab, const u16*& Bb, float& w, int& bi_, int& bj_) {
    int bj = (int)((sqrtf(8.0f * (float)g + 1.0f) - 1.0f) * 0.5f);
    while ((bj + 1) * (bj + 2) / 2 <= g) ++bj;
    while (bj * (bj + 1) / 2 > g) --bj;
    const int bi = g - bj * (bj + 1) / 2;
    Ab = tot + (size_t)(bi * 8 + wm * 4) * 4096 + off0;
    Bb = tot + (size_t)(bj * 8 + wn * 4) * 4096 + off0;
    float ww = ((bi < 32) == (bj < 32)) ? 1.0f : -1.0f;  // XX/YY vs XY/YX
    if (bi != bj) ww *= 2.0f;                            // symmetry weight
    w = ww; bi_ = bi; bj_ = bj;
  };

  double accsum = 0.0;
  bf16x8 a0[4], b0[4], a1[4], b1[4];

  int g = blockIdx.x;
  const u16 *Ab, *Bb; float w; int bi, bj;
  decode(g, Ab, Bb, w, bi, bj);
  #pragma unroll
  for (int tm = 0; tm < 4; ++tm) a0[tm] = *(const bf16x8*)(Ab + (size_t)tm * 4096);
  #pragma unroll
  for (int tn = 0; tn < 4; ++tn) b0[tn] = *(const bf16x8*)(Bb + (size_t)tn * 4096);

  for (;;) {
    f32x4 acc[4][4];
    #pragma unroll
    for (int tm = 0; tm < 4; ++tm)
      #pragma unroll
      for (int tn = 0; tn < 4; ++tn) {
        acc[tm][tn][0] = 0.f; acc[tm][tn][1] = 0.f;
        acc[tm][tn][2] = 0.f; acc[tm][tn][3] = 0.f;
      }

    // K-loop, 2-set ping-pong (set0 preloaded; last compute uses set1,
    // so set0 is free for the next tile's prologue loads afterwards)
    #pragma unroll
    for (int it = 0; it < 8; ++it) {
      bf16x8* ac = (it & 1) ? a1 : a0;
      bf16x8* bc = (it & 1) ? b1 : b0;
      bf16x8* an = (it & 1) ? a0 : a1;
      bf16x8* bn = (it & 1) ? b0 : b1;
      if (it < 7) {
        const size_t ko = (size_t)(it + 1) * 512;
        #pragma unroll
        for (int tm = 0; tm < 4; ++tm) an[tm] = *(const bf16x8*)(Ab + (size_t)tm * 4096 + ko);
        #pragma unroll
        for (int tn = 0; tn < 4; ++tn) bn[tn] = *(const bf16x8*)(Bb + (size_t)tn * 4096 + ko);
      }
      #pragma unroll
      for (int tm = 0; tm < 4; ++tm)
        #pragma unroll
        for (int tn = 0; tn < 4; ++tn)
          acc[tm][tn] = __builtin_amdgcn_mfma_f32_16x16x32_bf16(ac[tm], bc[tn], acc[tm][tn], 0, 0, 0);
    }

    // ---- next tile's set-0 loads issued BEFORE the epilogue (latency
    // drains for free under ~1500 cyc of epilogue VALU) ----
    const int gn = g + GRID;
    const bool more = (gn < NBLK);
    const u16 *Abn = Ab, *Bbn = Bb; float w2 = 0.f; int bin = bi, bjn = bj;
    if (more) {
      decode(gn, Abn, Bbn, w2, bin, bjn);
      #pragma unroll
      for (int tm = 0; tm < 4; ++tm) a0[tm] = *(const bf16x8*)(Abn + (size_t)tm * 4096);
      #pragma unroll
      for (int tn = 0; tn < 4; ++tn) b0[tn] = *(const bf16x8*)(Bbn + (size_t)tn * 4096);
    }

    // ---- epilogue: u = exp2(min((2a - sqi - sqj)*c2, 0)); 5-power sum ----
    const int gi0 = bi * 128 + wm * 64;
    const int gj0 = bj * 128 + wn * 64;
    f32x4 mi4[4];
    #pragma unroll
    for (int tm = 0; tm < 4; ++tm) {
      const f32x4 sqi = *(const f32x4*)&sq[gi0 + tm * 16 + quad * 4];
      mi4[tm][0] = sqi[0] * nc2; mi4[tm][1] = sqi[1] * nc2;
      mi4[tm][2] = sqi[2] * nc2; mi4[tm][3] = sqi[3] * nc2;
    }
    float lsum = 0.0f;
    #pragma unroll
    for (int tn = 0; tn < 4; ++tn) {
      const float mj = sq[gj0 + tn * 16 + l16] * nc2;
      #pragma unroll
      for (int tm = 0; tm < 4; ++tm) {
        const f32x4 av = acc[tm][tn];
        #pragma unroll
        for (int r = 0; r < 4; ++r) {
          float e = fminf(fmaf(av[r], c2x2, mi4[tm][r] + mj), 0.0f);
          float u = __builtin_amdgcn_exp2f(e);
          float u2 = u * u, u4 = u2 * u2, u8 = u4 * u4, u16v = u8 * u8;
          lsum += u + u2 + u4 + u8 + u16v;
        }
      }
    }
    accsum += (double)(lsum * w);

    if (!more) break;
    g = gn; Ab = Abn; Bb = Bbn; w = w2; bi = bin; bj = bjn;
  }

  // ---- once-per-block reduction & write (no atomics/fences) ----
  #pragma unroll
  for (int off = 32; off; off >>= 1) accsum += __shfl_down(accsum, off, 64);
  __shared__ double wsumd[4];
  if (lane == 0) wsumd[wave] = accsum;
  __syncthreads();
  if (tid == 0)
    part[blockIdx.x] = wsumd[0] + wsumd[1] + wsumd[2] + wsumd[3];
}

// ---- K3: final reduce of 512 partials -> scalar ----
__global__ __launch_bounds__(256) void k_final(const double* __restrict__ part,
                                               float* __restrict__ out) {
  __shared__ double red[256];
  const int t = threadIdx.x;
  double s = part[t] + part[t + 256];
  red[t] = s; __syncthreads();
  for (int off = 128; off; off >>= 1) { if (t < off) red[t] += red[t + off]; __syncthreads(); }
  if (t == 0) out[0] = (float)(red[0] / ((double)NX * (double)NX));
}

extern "C" void kernel_launch(void* const* d_in, const int* in_sizes, int n_in,
                              void* d_out, int out_size, void* d_ws, size_t ws_size,
                              hipStream_t stream) {
  const float* x = (const float*)d_in[0];
  const float* y = (const float*)d_in[1];
  char* ws = (char*)d_ws;
  u16*    tot  = (u16*)(ws + OFF_TOT);
  float*  sq   = (float*)(ws + OFF_SQ);
  float*  sqp  = (float*)(ws + OFF_SQPART);
  double* part = (double*)(ws + OFF_PART);
  float*  out  = (float*)d_out;

  hipLaunchKernelGGL(k_prep,  dim3(512),  dim3(256), 0, stream, x, y, tot, sq, sqp);
  hipLaunchKernelGGL(k_main,  dim3(GRID), dim3(256), 0, stream, tot, sq, sqp, part);
  hipLaunchKernelGGL(k_final, dim3(1),    dim3(256), 0, stream, part, out);
}

// Round 11
// 93.624 us; speedup vs baseline: 1.2098x; 1.0102x over previous
//
#include <hip/hip_runtime.h>
#include <stdint.h>

#define NTOT 8192
#define NX   4096
#define DIM  256
#define NBJ  64                      // 8192/128 tiles per dimension
#define NBLK (NBJ*(NBJ+1)/2)         // 2080 upper-triangle tiles
#define GRID 512                     // persistent blocks: 2/CU, 4-5 tiles each

typedef unsigned short u16;
typedef __attribute__((ext_vector_type(8))) short  bf16x8;
typedef __attribute__((ext_vector_type(8))) short  short8;
typedef __attribute__((ext_vector_type(4))) float  f32x4;

// ---- workspace layout (bytes) ----
#define OFF_TOT     0                        // u16[8192*256] FRAGMENT layout = 4,194,304
#define OFF_SQ      4194304                  // float[8192]
#define OFF_SQPART  (OFF_SQ + 32768)         // float[512]
#define OFF_PART    (OFF_SQPART + 2048)      // double[512]

// fragment layout: u16 offset = (r/16)*4096 + (k/8)*128 + (r%16)*8 + (k%8)
// => one wave's 16x32 MFMA A/B fragment slice = 1KB contiguous, lane-coalesced.

__device__ __forceinline__ u16 f2bf(float f) {
  union { float f; unsigned int u; } v; v.f = f;
  unsigned int u = v.u;
  u += 0x7fffu + ((u >> 16) & 1u);           // round-to-nearest-even
  return (u16)(u >> 16);
}

// ---- K1: prep. 512 blocks x 256; block = 16 rows = one fragment chunk.
// Coalesced float4 reads -> bf16 -> LDS bounce in fragment order -> coalesced
// 16B global writes. Row norms -> sq + per-block partial. NO atomics/fences.
__global__ __launch_bounds__(256) void k_prep(const float* __restrict__ x,
                                              const float* __restrict__ y,
                                              u16* __restrict__ tot,
                                              float* __restrict__ sq,
                                              float* __restrict__ sqpart) {
  __shared__ u16   tile[4096];      // one 16-row fragment chunk image
  __shared__ float sred[16];
  const int t  = threadIdx.x;
  const int rr = t >> 4;            // row within chunk (0..15)
  const int cg = t & 15;            // 16-col group
  const int r  = blockIdx.x * 16 + rr;

  const float* row = (r < NX) ? (x + (size_t)r * DIM) : (y + (size_t)(r - NX) * DIM);
  const float4* rp = (const float4*)row + cg * 4;
  const float4 p0 = rp[0], p1 = rp[1], p2 = rp[2], p3 = rp[3];

  short8 h0, h1;
  h0[0]=(short)f2bf(p0.x); h0[1]=(short)f2bf(p0.y); h0[2]=(short)f2bf(p0.z); h0[3]=(short)f2bf(p0.w);
  h0[4]=(short)f2bf(p1.x); h0[5]=(short)f2bf(p1.y); h0[6]=(short)f2bf(p1.z); h0[7]=(short)f2bf(p1.w);
  h1[0]=(short)f2bf(p2.x); h1[1]=(short)f2bf(p2.y); h1[2]=(short)f2bf(p2.z); h1[3]=(short)f2bf(p2.w);
  h1[4]=(short)f2bf(p3.x); h1[5]=(short)f2bf(p3.y); h1[6]=(short)f2bf(p3.z); h1[7]=(short)f2bf(p3.w);
  // o(r,c) = (c>>3)*128 + rr*8 ; cols cg*16..+7 and cg*16+8..+15
  *(short8*)&tile[cg * 256 + rr * 8]       = h0;
  *(short8*)&tile[cg * 256 + 128 + rr * 8] = h1;

  float s = p0.x*p0.x + p0.y*p0.y + p0.z*p0.z + p0.w*p0.w
          + p1.x*p1.x + p1.y*p1.y + p1.z*p1.z + p1.w*p1.w
          + p2.x*p2.x + p2.y*p2.y + p2.z*p2.z + p2.w*p2.w
          + p3.x*p3.x + p3.y*p3.y + p3.z*p3.z + p3.w*p3.w;
  #pragma unroll
  for (int k = 8; k; k >>= 1) s += __shfl_down(s, k, 64);   // reduce over 16 col-lanes
  if (cg == 0) { sq[r] = s; sred[rr] = s; }
  __syncthreads();

  u16* chunk = tot + (size_t)blockIdx.x * 4096;
  *(uint4*)(chunk + t * 8)        = *(const uint4*)&tile[t * 8];
  *(uint4*)(chunk + 2048 + t * 8) = *(const uint4*)&tile[2048 + t * 8];
  if (t == 0) {
    float ss = 0.f;
    #pragma unroll
    for (int i = 0; i < 16; ++i) ss += sred[i];
    sqpart[blockIdx.x] = ss;
  }
}

// ---- K2: persistent tile-pipelined gram + 5-kernel RBF + signed sum.
// 512 blocks, tiles g, g+512, ... Depth-2 K-prefetch (3-set rotation:
// ~310 cyc cover vs ~200 cyc L2 latency; R10's depth-1 gave only ~78) +
// cross-tile prologue (next tile's slices 0,1 issued before the ~1600 cyc
// epilogue). Zero barriers/atomics/fences in hot path (R6 lesson);
// lb(256,2) for spill-free allocation (R5/R8/R9 lessons).
__global__ __launch_bounds__(256, 2) void k_main(const u16* __restrict__ tot,
                                                 const float* __restrict__ sq,
                                                 const float* __restrict__ sqpart,
                                                 double* __restrict__ part) {
  const int tid = threadIdx.x, wave = tid >> 6, lane = tid & 63;
  const int quad = lane >> 4, l16 = lane & 15;
  const int wm = wave >> 1, wn = wave & 1;
  const int off0 = quad * 128 + l16 * 8;     // within-chunk fragment offset (u16)

  // ---- per-block c2 from sqpart[512] (fence-free redundant compute) ----
  float sp = sqpart[tid] + sqpart[tid + 256];
  #pragma unroll
  for (int off = 32; off; off >>= 1) sp += __shfl_down(sp, off, 64);
  __shared__ float spw[4];
  if (lane == 0) spw[wave] = sp;
  __syncthreads();
  const double S1 = (double)spw[0] + (double)spw[1] + (double)spw[2] + (double)spw[3];
  const double n  = (double)NTOT;
  const double bwd = 2.0 * n * S1 / (n * n - n) * 0.25;  // colsum term dropped (1e-4 rel)
  const float  c2  = (float)(1.0 / (16.0 * bwd * 0.6931471805599453));
  const float  nc2 = -c2, c2x2 = 2.0f * c2;

  // tile decode: g -> (bi<=bj), frag bases, weight
  auto decode = [&](int g, const u16*& Ab, const u16*& Bb, float& w, int& bi_, int& bj_) {
    int bj = (int)((sqrtf(8.0f * (float)g + 1.0f) - 1.0f) * 0.5f);
    while ((bj + 1) * (bj + 2) / 2 <= g) ++bj;
    while (bj * (bj + 1) / 2 > g) --bj;
    const int bi = g - bj * (bj + 1) / 2;
    Ab = tot + (size_t)(bi * 8 + wm * 4) * 4096 + off0;
    Bb = tot + (size_t)(bj * 8 + wn * 4) * 4096 + off0;
    float ww = ((bi < 32) == (bj < 32)) ? 1.0f : -1.0f;  // XX/YY vs XY/YX
    if (bi != bj) ww *= 2.0f;                            // symmetry weight
    w = ww; bi_ = bi; bj_ = bj;
  };

  double accsum = 0.0;
  bf16x8 a[3][4], b[3][4];          // 3-set rotation: slice it -> set (it%3)

  int g = blockIdx.x;
  const u16 *Ab, *Bb; float w; int bi, bj;
  decode(g, Ab, Bb, w, bi, bj);
  #pragma unroll
  for (int tm = 0; tm < 4; ++tm) {
    a[0][tm] = *(const bf16x8*)(Ab + (size_t)tm * 4096);
    b[0][tm] = *(const bf16x8*)(Bb + (size_t)tm * 4096);
    a[1][tm] = *(const bf16x8*)(Ab + (size_t)tm * 4096 + 512);
    b[1][tm] = *(const bf16x8*)(Bb + (size_t)tm * 4096 + 512);
  }

  for (;;) {
    f32x4 acc[4][4];
    #pragma unroll
    for (int tm = 0; tm < 4; ++tm)
      #pragma unroll
      for (int tn = 0; tn < 4; ++tn) {
        acc[tm][tn][0] = 0.f; acc[tm][tn][1] = 0.f;
        acc[tm][tn][2] = 0.f; acc[tm][tn][3] = 0.f;
      }

    // K-loop: use set(it%3); prefetch slice it+2 into set((it+2)%3).
    // Slices 0,1 preloaded (first tile: above; later: during prev epilogue).
    #pragma unroll
    for (int it = 0; it < 8; ++it) {
      const int cur = it % 3;
      const int nxt = (it + 2) % 3;
      if (it < 6) {
        const size_t ko = (size_t)(it + 2) * 512;
        #pragma unroll
        for (int tm = 0; tm < 4; ++tm) {
          a[nxt][tm] = *(const bf16x8*)(Ab + (size_t)tm * 4096 + ko);
          b[nxt][tm] = *(const bf16x8*)(Bb + (size_t)tm * 4096 + ko);
        }
      }
      #pragma unroll
      for (int tm = 0; tm < 4; ++tm)
        #pragma unroll
        for (int tn = 0; tn < 4; ++tn)
          acc[tm][tn] = __builtin_amdgcn_mfma_f32_16x16x32_bf16(a[cur][tm], b[cur][tn], acc[tm][tn], 0, 0, 0);
    }

    // ---- next tile's slices 0,1 issued BEFORE the epilogue (sets 0,1 are
    // free after it=6/it=7 MFMAs issue; ~1600 cyc epilogue hides latency) ----
    const int gn = g + GRID;
    const bool more = (gn < NBLK);
    const u16 *Abn = Ab, *Bbn = Bb; float w2 = 0.f; int bin = bi, bjn = bj;
    if (more) {
      decode(gn, Abn, Bbn, w2, bin, bjn);
      #pragma unroll
      for (int tm = 0; tm < 4; ++tm) {
        a[0][tm] = *(const bf16x8*)(Abn + (size_t)tm * 4096);
        b[0][tm] = *(const bf16x8*)(Bbn + (size_t)tm * 4096);
        a[1][tm] = *(const bf16x8*)(Abn + (size_t)tm * 4096 + 512);
        b[1][tm] = *(const bf16x8*)(Bbn + (size_t)tm * 4096 + 512);
      }
    }

    // ---- epilogue: u = exp2(min((2a - sqi - sqj)*c2, 0)); 5-power sum ----
    const int gi0 = bi * 128 + wm * 64;
    const int gj0 = bj * 128 + wn * 64;
    f32x4 mi4[4];
    #pragma unroll
    for (int tm = 0; tm < 4; ++tm) {
      const f32x4 sqi = *(const f32x4*)&sq[gi0 + tm * 16 + quad * 4];
      mi4[tm][0] = sqi[0] * nc2; mi4[tm][1] = sqi[1] * nc2;
      mi4[tm][2] = sqi[2] * nc2; mi4[tm][3] = sqi[3] * nc2;
    }
    float lsum = 0.0f;
    #pragma unroll
    for (int tn = 0; tn < 4; ++tn) {
      const float mj = sq[gj0 + tn * 16 + l16] * nc2;
      #pragma unroll
      for (int tm = 0; tm < 4; ++tm) {
        const f32x4 av = acc[tm][tn];
        #pragma unroll
        for (int r = 0; r < 4; ++r) {
          float e = fminf(fmaf(av[r], c2x2, mi4[tm][r] + mj), 0.0f);
          float u = __builtin_amdgcn_exp2f(e);
          float u2 = u * u, u4 = u2 * u2, u8 = u4 * u4, u16v = u8 * u8;
          lsum += u + u2 + u4 + u8 + u16v;
        }
      }
    }
    accsum += (double)(lsum * w);

    if (!more) break;
    g = gn; Ab = Abn; Bb = Bbn; w = w2; bi = bin; bj = bjn;
  }

  // ---- once-per-block reduction & write (no atomics/fences) ----
  #pragma unroll
  for (int off = 32; off; off >>= 1) accsum += __shfl_down(accsum, off, 64);
  __shared__ double wsumd[4];
  if (lane == 0) wsumd[wave] = accsum;
  __syncthreads();
  if (tid == 0)
    part[blockIdx.x] = wsumd[0] + wsumd[1] + wsumd[2] + wsumd[3];
}

// ---- K3: final reduce of 512 partials -> scalar ----
__global__ __launch_bounds__(256) void k_final(const double* __restrict__ part,
                                               float* __restrict__ out) {
  __shared__ double red[256];
  const int t = threadIdx.x;
  double s = part[t] + part[t + 256];
  red[t] = s; __syncthreads();
  for (int off = 128; off; off >>= 1) { if (t < off) red[t] += red[t + off]; __syncthreads(); }
  if (t == 0) out[0] = (float)(red[0] / ((double)NX * (double)NX));
}

extern "C" void kernel_launch(void* const* d_in, const int* in_sizes, int n_in,
                              void* d_out, int out_size, void* d_ws, size_t ws_size,
                              hipStream_t stream) {
  const float* x = (const float*)d_in[0];
  const float* y = (const float*)d_in[1];
  char* ws = (char*)d_ws;
  u16*    tot  = (u16*)(ws + OFF_TOT);
  float*  sq   = (float*)(ws + OFF_SQ);
  float*  sqp  = (float*)(ws + OFF_SQPART);
  double* part = (double*)(ws + OFF_PART);
  float*  out  = (float*)d_out;

  hipLaunchKernelGGL(k_prep,  dim3(512),  dim3(256), 0, stream, x, y, tot, sq, sqp);
  hipLaunchKernelGGL(k_main,  dim3(GRID), dim3(256), 0, stream, tot, sq, sqp, part);
  hipLaunchKernelGGL(k_final, dim3(1),    dim3(256), 0, stream, part, out);
}